// Round 7
// baseline (969.717 us; speedup 1.0000x reference)
//
#include <hip/hip_runtime.h>
#include <hip/hip_bf16.h>
#include <math.h>

#define MOTIF  283
#define KPAD   288
#define HIDDEN 256
#define DEPTH  7
#define KPROF  20
#define CHUNK  512
#define NCHUNK 256
#define NTOK   131072
#define BK     32

using bf16 = __hip_bfloat16;
typedef short bf16x8 __attribute__((ext_vector_type(8)));
typedef float f32x4  __attribute__((ext_vector_type(4)));

// async global->LDS, 16B per lane; LDS dest = wave-uniform base + lane*16
#define GLD_LDS(g, l) __builtin_amdgcn_global_load_lds( \
    (const __attribute__((address_space(1))) void*)(g), \
    (__attribute__((address_space(3))) void*)(l), 16, 0, 0)

__device__ __forceinline__ float gelu_res(float c){
  return 0.5f * c * (1.0f + erff(c * 0.70710678118654752f)) + c;   // gelu(c)+c
}

// ------------------------------------------------------------- prep kernels
// wtowT[layer][tap][co][ci] (bf16) from tower_w[layer][co][ci][tap] (f32)
__global__ __launch_bounds__(256) void k_prep_tower(
    const float* __restrict__ w, bf16* __restrict__ wt){
  const int idx = blockIdx.x * 256 + threadIdx.x;
  if (idx < DEPTH * 3 * HIDDEN * HIDDEN){
    const int ci = idx & 255;
    const int co = (idx >> 8) & 255;
    const int lt = idx >> 16;             // layer*3 + tap
    const int layer = lt / 3, tap = lt % 3;
    wt[idx] = __float2bfloat16(
        w[(((size_t)layer * HIDDEN + co) * HIDDEN + ci) * 3 + tap]);
  }
}

// wprojT[co][KPAD] bf16, zero-padded m>=283
__global__ __launch_bounds__(256) void k_prep_wproj(
    const float* __restrict__ w, bf16* __restrict__ wt){
  const int idx = blockIdx.x * 256 + threadIdx.x;
  if (idx < HIDDEN * KPAD){
    const int co = idx / KPAD, m = idx % KPAD;
    wt[idx] = __float2bfloat16(m < MOTIF ? w[(size_t)co * MOTIF + m] : 0.0f);
  }
}

// wheadT[k][ci] bf16 (rows 0..19 wprof, 20 watpm, 21..31 zero) + zero the
// 4 KB zero-page every call (ws is re-poisoned to 0xAA before each launch)
__global__ __launch_bounds__(256) void k_prep_whead(
    const float* __restrict__ wprof, const float* __restrict__ watpm,
    bf16* __restrict__ wh, bf16* __restrict__ zp){
  const int idx = blockIdx.x * 256 + threadIdx.x;
  if (idx < 2048) zp[idx] = __float2bfloat16(0.0f);
  if (idx < 32 * 256){
    const int k = idx >> 8, ci = idx & 255;
    float v = 0.0f;
    if (k < KPROF) v = wprof[ci * KPROF + k];
    else if (k == KPROF) v = watpm[ci];
    wh[idx] = __float2bfloat16(v);
  }
}

// ------------------------------------------------------------- projection
// m97-shape GEMM: tile 128co x 128tok, 4 waves 2x2 (64x64 each, acc 4x4 = 64
// AGPR). A (wprojT, zero-padded K=288) staged via global_load_lds with the
// global-side XOR chunk swizzle; B (x fp32) staged via scalar-load + cvt +
// swizzled ds_write_b128 (x rows are only 4B-aligned). 2-barrier K-loop.
__global__ __launch_bounds__(256, 4) void k_proj(
    const float* __restrict__ x, const bf16* __restrict__ wprojT,
    bf16* __restrict__ h0){
  __shared__ __align__(16) bf16 As[128 * BK];   // 8 KB [co_r][m]
  __shared__ __align__(16) bf16 Bs[128 * BK];   // 8 KB [tok_r][m]
  const int t0  = blockIdx.x * 128;
  const int co0 = blockIdx.y * 128;
  const int tid = threadIdx.x;
  const int wid = tid >> 6, lane = tid & 63;
  const int lr = lane & 15, kq = lane >> 4;
  const int mw = wid & 1, nw = wid >> 1;

  // A staging pointers (2 rounds of 256 lane-slots)
  const bf16* gA[2];
  #pragma unroll
  for (int j = 0; j < 2; ++j){
    const int i   = j * 256 + tid;
    const int row = i >> 2, c = i & 3;
    const int cc  = c ^ (row & 3);            // global-side XOR swizzle
    gA[j] = wprojT + (size_t)(co0 + row) * KPAD + cc * 8;
  }

  // B staging: 2 threads per token row, 16 m-values each (two 16B chunks)
  const int brow = tid >> 1, bhalf = tid & 1;
  const float* xrow = x + (size_t)(t0 + brow) * MOTIF;
  bf16* bdst0 = Bs + brow * BK + (((bhalf * 2)     ^ (brow & 3)) << 3);
  bf16* bdst1 = Bs + brow * BK + (((bhalf * 2 + 1) ^ (brow & 3)) << 3);

  f32x4 acc[4][4];
  #pragma unroll
  for (int mt = 0; mt < 4; ++mt)
    #pragma unroll
    for (int nt = 0; nt < 4; ++nt) acc[mt][nt] = (f32x4){0.f, 0.f, 0.f, 0.f};

  const int sw = (kq ^ (lr & 3)) << 3;
  const bf16* Ab = As + (mw * 64 + lr) * BK + sw;
  const bf16* Bb = Bs + (nw * 64 + lr) * BK + sw;

  for (int m0 = 0; m0 < KPAD; m0 += BK){
    __syncthreads();
    GLD_LDS(gA[0], As + (wid * 64) * 8);
    GLD_LDS(gA[1], As + (256 + wid * 64) * 8);
    gA[0] += BK; gA[1] += BK;

    bf16 ov[16];
    const int mbase = m0 + bhalf * 16;
    if (m0 + BK <= MOTIF){
      #pragma unroll
      for (int e = 0; e < 16; ++e) ov[e] = __float2bfloat16(xrow[mbase + e]);
    } else {
      #pragma unroll
      for (int e = 0; e < 16; ++e){
        const int m = mbase + e;
        ov[e] = __float2bfloat16(m < MOTIF ? xrow[m] : 0.0f);
      }
    }
    *(uint4*)bdst0 = *(uint4*)(ov);
    *(uint4*)bdst1 = *(uint4*)(ov + 8);
    __syncthreads();

    bf16x8 a[4], b[4];
    #pragma unroll
    for (int mt = 0; mt < 4; ++mt) a[mt] = *(const bf16x8*)(Ab + mt * 512);
    #pragma unroll
    for (int nt = 0; nt < 4; ++nt) b[nt] = *(const bf16x8*)(Bb + nt * 512);
    #pragma unroll
    for (int mt = 0; mt < 4; ++mt)
      #pragma unroll
      for (int nt = 0; nt < 4; ++nt)
        acc[mt][nt] = __builtin_amdgcn_mfma_f32_16x16x32_bf16(
            a[mt], b[nt], acc[mt][nt], 0, 0, 0);
  }

  #pragma unroll
  for (int mt = 0; mt < 4; ++mt){
    const int co = co0 + mw * 64 + mt * 16 + kq * 4;
    #pragma unroll
    for (int nt = 0; nt < 4; ++nt){
      const int tok = t0 + nw * 64 + nt * 16 + lr;
      bf16 ov[4];
      #pragma unroll
      for (int r = 0; r < 4; ++r) ov[r] = __float2bfloat16(acc[mt][nt][r]);
      *(uint2*)(h0 + (size_t)tok * HIDDEN + co) = *(uint2*)ov;
    }
  }
}

// ------------------------------------------------------------- conv tower
// m97-shape GEMM: tile 128co x 128l, 4 waves 2x2 (64x64 each, acc 4x4 = 64
// AGPR), A+B staged via global_load_lds(16B), 2-barrier K-loop (8 iters of
// BK=32, 3 taps inside). XOR column swizzle (cc = c ^ (row&3)) applied on the
// GLOBAL side so LDS stays lane-contiguous for global_load_lds yet fragment
// ds_read_b128s are bank-conflict-free. OOB tap rows read a zero page.
__global__ __launch_bounds__(256, 3) void k_conv(
    const bf16* __restrict__ hin, bf16* __restrict__ hout,
    const bf16* __restrict__ wl,     // [3][256 co][256 ci] this layer
    const float* __restrict__ bias, const bf16* __restrict__ zp, int dil){
  __shared__ __align__(16) bf16 As[3 * 128 * BK];   // 24 KB [tap][co_r][ci]
  __shared__ __align__(16) bf16 Bs[3 * 128 * BK];   // 24 KB [tap][l_r][ci]
  const int n   = blockIdx.z;
  const int co0 = blockIdx.y * 128;
  const int l0  = blockIdx.x * 128;
  const int tid = threadIdx.x;
  const int wid = tid >> 6, lane = tid & 63;
  const int lr = lane & 15, kq = lane >> 4;
  const int mw = wid & 1, nw = wid >> 1;

  const bf16* hbase = hin + (size_t)n * CHUNK * HIDDEN;

  // per-thread staging pointers (advance by BK elems per K-iter)
  const bf16* gA[6]; const bf16* gB[6]; int stepB[6];
  #pragma unroll
  for (int j = 0; j < 6; ++j){
    const int i   = j * 256 + tid;
    const int row = i >> 2, c = i & 3;
    const int cc  = c ^ (row & 3);          // global-side XOR swizzle
    const int tap = row >> 7;
    const int r   = row & 127;
    gA[j] = wl + ((size_t)(tap * 256 + co0 + r) << 8) + cc * 8;
    const int l = l0 + r + (tap - 1) * dil;
    const bool v = (unsigned)l < CHUNK;
    gB[j] = v ? hbase + ((size_t)l << 8) + cc * 8 : zp + ((i & 255) * 8);
    stepB[j] = v ? BK : 0;
  }

  f32x4 acc[4][4];
  #pragma unroll
  for (int mt = 0; mt < 4; ++mt)
    #pragma unroll
    for (int nt = 0; nt < 4; ++nt) acc[mt][nt] = (f32x4){0.f, 0.f, 0.f, 0.f};

  // fragment read bases (constant across K-iters; tap/mt offsets fold to imm)
  const int sw = (kq ^ (lr & 3)) << 3;
  const bf16* Ab = As + (mw * 64 + lr) * BK + sw;
  const bf16* Bb = Bs + (nw * 64 + lr) * BK + sw;

  // block-uniform whole-tap skips (staging still runs; zeros are harmless)
  const bool do0 = (l0 + 127 - dil) >= 0;       // false only l0=0, dil=128
  const bool do2 = (l0 + dil) < CHUNK;          // false only l0=384, dil=128

  for (int it = 0; it < HIDDEN / BK; ++it){
    __syncthreads();
    #pragma unroll
    for (int j = 0; j < 6; ++j){
      GLD_LDS(gA[j], As + (j * 256 + wid * 64) * 8);
      GLD_LDS(gB[j], Bs + (j * 256 + wid * 64) * 8);
    }
    __syncthreads();

    #pragma unroll
    for (int t = 0; t < 3; ++t){
      if (t == 0 && !do0) continue;
      if (t == 2 && !do2) continue;
      bf16x8 a[4], b[4];
      #pragma unroll
      for (int mt = 0; mt < 4; ++mt)
        a[mt] = *(const bf16x8*)(Ab + t * 4096 + mt * 512);
      #pragma unroll
      for (int nt = 0; nt < 4; ++nt)
        b[nt] = *(const bf16x8*)(Bb + t * 4096 + nt * 512);
      #pragma unroll
      for (int mt = 0; mt < 4; ++mt)
        #pragma unroll
        for (int nt = 0; nt < 4; ++nt)
          acc[mt][nt] = __builtin_amdgcn_mfma_f32_16x16x32_bf16(
              a[mt], b[nt], acc[mt][nt], 0, 0, 0);
    }

    #pragma unroll
    for (int j = 0; j < 6; ++j){ gA[j] += BK; gB[j] += stepB[j]; }
  }

  bf16* obase = hout + (size_t)n * CHUNK * HIDDEN;
  #pragma unroll
  for (int mt = 0; mt < 4; ++mt){
    const int co = co0 + mw * 64 + mt * 16 + kq * 4;
    const float b0 = bias[co], b1 = bias[co + 1];
    const float b2 = bias[co + 2], b3 = bias[co + 3];
    #pragma unroll
    for (int nt = 0; nt < 4; ++nt){
      const int l = l0 + nw * 64 + nt * 16 + lr;
      bf16 ov[4];
      ov[0] = __float2bfloat16(gelu_res(acc[mt][nt][0] + b0));
      ov[1] = __float2bfloat16(gelu_res(acc[mt][nt][1] + b1));
      ov[2] = __float2bfloat16(gelu_res(acc[mt][nt][2] + b2));
      ov[3] = __float2bfloat16(gelu_res(acc[mt][nt][3] + b3));
      *(uint2*)(obase + (size_t)l * HIDDEN + co) = *(uint2*)ov;
    }
  }
}

// ------------------------------------------------------------- head GEMM
__global__ __launch_bounds__(256, 2) void k_head(
    const bf16* __restrict__ h, const bf16* __restrict__ wheadT,
    float* __restrict__ PT){
  __shared__ __align__(16) bf16 Xs[128 * BK];     // 8 KB
  __shared__ __align__(16) bf16 Wh[32 * 256];     // 16 KB
  const int t0 = blockIdx.x * 128;
  const int tid = threadIdx.x;
  const int wid = tid >> 6, lane = tid & 63;
  const int lr = lane & 15, kq = lane >> 4;
  const int mw = wid & 1, nw = wid >> 1;

  for (int i = tid; i < 1024; i += 256)
    ((uint4*)Wh)[i] = ((const uint4*)wheadT)[i];

  f32x4 acc[4];
  #pragma unroll
  for (int mt = 0; mt < 4; ++mt) acc[mt] = (f32x4){0.f, 0.f, 0.f, 0.f};

  for (int ci0 = 0; ci0 < HIDDEN; ci0 += BK){
    __syncthreads();
    for (int i = tid; i < 512; i += 256){
      const int row = i >> 2, q = i & 3;
      *(uint4*)(Xs + row * BK + q * 8) =
          *(const uint4*)(h + (size_t)(t0 + row) * HIDDEN + ci0 + q * 8);
    }
    __syncthreads();
    const bf16x8 b = *(const bf16x8*)(Wh + (nw * 16 + lr) * 256 + ci0 + kq * 8);
    #pragma unroll
    for (int mt = 0; mt < 4; ++mt){
      const bf16x8 a = *(const bf16x8*)(Xs + (mw * 64 + mt * 16 + lr) * BK + kq * 8);
      acc[mt] = __builtin_amdgcn_mfma_f32_16x16x32_bf16(a, b, acc[mt], 0, 0, 0);
    }
  }
  const int k_out = nw * 16 + lr;
  #pragma unroll
  for (int mt = 0; mt < 4; ++mt){
    const int tok = t0 + mw * 64 + mt * 16 + kq * 4;
    *(f32x4*)(PT + (size_t)k_out * NTOK + tok) = acc[mt];
  }
}

// ------------------------------------------------------------- tap combine
__global__ __launch_bounds__(256) void k_combine(
    const float* __restrict__ PT, const float* __restrict__ bprof,
    float* __restrict__ out){
  const int t = blockIdx.x * 256 + threadIdx.x;
  const int n = t >> 9, l = t & 511;
  float acc = bprof[0];
  const float* base = PT + ((size_t)n << 9);
  #pragma unroll
  for (int k = 0; k < KPROF; ++k){
    const int j = l + k - 9;
    if ((unsigned)j < CHUNK) acc += base[(size_t)k * NTOK + j];
  }
  out[NCHUNK + t] = acc;
}

// ------------------------------------------------------------- atpm pool
__global__ __launch_bounds__(256) void k_atpm(
    const float* __restrict__ PT, const float* __restrict__ batpm,
    const int* __restrict__ n_peaks, float* __restrict__ out){
  __shared__ float red[4];
  const int n = blockIdx.x, tid = threadIdx.x;
  const float* row = PT + (size_t)KPROF * NTOK + ((size_t)n << 9);
  float p = row[tid] + row[tid + 256];
  #pragma unroll
  for (int off = 32; off > 0; off >>= 1) p += __shfl_down(p, off, 64);
  if ((tid & 63) == 0) red[tid >> 6] = p;
  __syncthreads();
  if (tid == 0){
    const float s = red[0] + red[1] + red[2] + red[3];
    const float a = s * (1.0f / 512.0f) + batpm[0];
    out[n] = ((n & 127) < n_peaks[n >> 7]) ? a : 0.0f;
  }
}

// ------------------------------------------------------------- launcher
extern "C" void kernel_launch(void* const* d_in, const int* in_sizes, int n_in,
                              void* d_out, int out_size, void* d_ws, size_t ws_size,
                              hipStream_t stream){
  const float* x       = (const float*)d_in[0];
  const float* w_proj  = (const float*)d_in[1];
  const float* tower_w = (const float*)d_in[2];
  const float* tower_b = (const float*)d_in[3];
  const float* w_prof  = (const float*)d_in[4];
  const float* b_prof  = (const float*)d_in[5];
  const float* w_atpm  = (const float*)d_in[6];
  const float* b_atpm  = (const float*)d_in[7];
  const int*   n_peaks = (const int*)d_in[8];
  float* out = (float*)d_out;

  char* ws = (char*)d_ws;
  bf16*  h0     = (bf16*)ws;                        // 67108864 B
  bf16*  h1     = (bf16*)(ws + 67108864);           // 67108864 B
  float* PT     = (float*)(ws + 134217728);         // 16777216 B
  bf16*  wtowT  = (bf16*)(ws + 150994944);          // 2752512 B
  bf16*  wheadT = (bf16*)(ws + 153747456);          // 16384 B
  bf16*  wprojT = (bf16*)(ws + 153763840);          // 147456 B
  bf16*  zp     = (bf16*)(ws + 153911296);          // 4096 B zero page

  k_prep_tower<<<5376, 256, 0, stream>>>(tower_w, wtowT);
  k_prep_wproj<<<(HIDDEN * KPAD + 255) / 256, 256, 0, stream>>>(w_proj, wprojT);
  k_prep_whead<<<32, 256, 0, stream>>>(w_prof, w_atpm, wheadT, zp);

  k_proj<<<dim3(NTOK / 128, 2), 256, 0, stream>>>(x, wprojT, h0);

  bf16* cur = h0; bf16* nxt = h1;
  for (int i = 0; i < DEPTH; ++i){
    k_conv<<<dim3(CHUNK / 128, 2, NCHUNK), 256, 0, stream>>>(
        cur, nxt, wtowT + (size_t)i * 3 * HIDDEN * HIDDEN,
        tower_b + i * HIDDEN, zp, 2 << i);
    bf16* t = cur; cur = nxt; nxt = t;
  }

  k_head<<<1024, 256, 0, stream>>>(cur, wheadT, PT);
  k_combine<<<512, 256, 0, stream>>>(PT, b_prof, out);
  k_atpm<<<256, 256, 0, stream>>>(PT, b_atpm, n_peaks, out);
}